// Round 3
// baseline (3341.091 us; speedup 1.0000x reference)
//
#include <hip/hip_runtime.h>

// ---------------------------------------------------------------------------
// Problem constants: B=2, L=1024, D=1024, H=16, DK=DV=64
// ---------------------------------------------------------------------------

#define TILE_M 64
#define TILE_N 64
#define TILE_K 16

struct GemmSlot { const float* W; const float* bias; float* out; int mode; };
struct GemmBatch { GemmSlot s[4]; };

__device__ __forceinline__ float silu_(float x) {
  return x / (1.f + __expf(-x));
}
__device__ __forceinline__ float sigm_(float x) {
  return 1.f / (1.f + __expf(-x));
}
__device__ __forceinline__ float rdl_(float v, int l) {
  return __int_as_float(__builtin_amdgcn_readlane(__float_as_int(v), l));
}

// ---------------------------------------------------------------------------
// Generic fp32 GEMM: C = act(A[M,K] @ W[K,N] + bias), act/store per mode.
// mode 0: raw, linear store; mode 1: silu, linear; mode 2: silu, scatter BHLd
// ---------------------------------------------------------------------------
__global__ __launch_bounds__(256) void gemm_act(
    const float* __restrict__ A, GemmBatch gb, int M, int N, int K)
{
  const GemmSlot sl = gb.s[blockIdx.z];
  const float* __restrict__ W = sl.W;

  __shared__ float As[TILE_K][TILE_M + 4];
  __shared__ float Ws[TILE_K][TILE_N];

  const int tid = threadIdx.x;
  const int bm = blockIdx.x * TILE_M;
  const int bn = blockIdx.y * TILE_N;
  const int tm = (tid >> 4) << 2;
  const int tn = (tid & 15) << 2;
  const int la_r = tid >> 2;
  const int la_c = (tid & 3) << 2;
  const int lw_r = tid >> 4;
  const int lw_c = (tid & 15) << 2;

  float acc[4][4] = {{0.f,0.f,0.f,0.f},{0.f,0.f,0.f,0.f},
                     {0.f,0.f,0.f,0.f},{0.f,0.f,0.f,0.f}};

  for (int kb = 0; kb < K; kb += TILE_K) {
    float4 av = *(const float4*)&A[(size_t)(bm + la_r) * K + kb + la_c];
    float4 wv = *(const float4*)&W[(size_t)(kb + lw_r) * N + bn + lw_c];
    __syncthreads();
    As[la_c + 0][la_r] = av.x;
    As[la_c + 1][la_r] = av.y;
    As[la_c + 2][la_r] = av.z;
    As[la_c + 3][la_r] = av.w;
    *(float4*)&Ws[lw_r][lw_c] = wv;
    __syncthreads();
#pragma unroll
    for (int kk = 0; kk < TILE_K; ++kk) {
      float4 a = *(const float4*)&As[kk][tm];
      float4 b = *(const float4*)&Ws[kk][tn];
      acc[0][0] = fmaf(a.x, b.x, acc[0][0]);
      acc[0][1] = fmaf(a.x, b.y, acc[0][1]);
      acc[0][2] = fmaf(a.x, b.z, acc[0][2]);
      acc[0][3] = fmaf(a.x, b.w, acc[0][3]);
      acc[1][0] = fmaf(a.y, b.x, acc[1][0]);
      acc[1][1] = fmaf(a.y, b.y, acc[1][1]);
      acc[1][2] = fmaf(a.y, b.z, acc[1][2]);
      acc[1][3] = fmaf(a.y, b.w, acc[1][3]);
      acc[2][0] = fmaf(a.z, b.x, acc[2][0]);
      acc[2][1] = fmaf(a.z, b.y, acc[2][1]);
      acc[2][2] = fmaf(a.z, b.z, acc[2][2]);
      acc[2][3] = fmaf(a.z, b.w, acc[2][3]);
      acc[3][0] = fmaf(a.w, b.x, acc[3][0]);
      acc[3][1] = fmaf(a.w, b.y, acc[3][1]);
      acc[3][2] = fmaf(a.w, b.z, acc[3][2]);
      acc[3][3] = fmaf(a.w, b.w, acc[3][3]);
    }
  }

  const float* bias = sl.bias;
  float* out = sl.out;
  const int mode = sl.mode;
#pragma unroll
  for (int i = 0; i < 4; ++i) {
#pragma unroll
    for (int j = 0; j < 4; ++j) {
      int m = bm + tm + i, n = bn + tn + j;
      float c = acc[i][j] + bias[n];
      if (mode >= 1) c = silu_(c);
      if (mode == 2) {
        int h = n >> 6, d = n & 63;
        int b = m >> 10, l = m & 1023;
        out[(((size_t)(b * 16 + h)) * 1024 + l) * 64 + d] = c;
      } else {
        out[(size_t)m * N + n] = c;
      }
    }
  }
}

// ---------------------------------------------------------------------------
// Scalar projections, packed: scl[bh][t][8], slot 0=beta,1=fd,2=sd,3=fg,4=sg
// ---------------------------------------------------------------------------
__global__ __launch_bounds__(256) void scalar_proj(
    const float* __restrict__ hs,
    const float* __restrict__ Wb,  const float* __restrict__ bb,
    const float* __restrict__ Wfd, const float* __restrict__ bfd, const float* __restrict__ fdb,
    const float* __restrict__ Wsd, const float* __restrict__ bsd, const float* __restrict__ sdb,
    const float* __restrict__ Wfg, const float* __restrict__ bfg,
    const float* __restrict__ Wsg, const float* __restrict__ bsg,
    float* __restrict__ scl)
{
  int gid = blockIdx.x * 256 + threadIdx.x;  // < 2048*80
  int m = gid / 80;
  int c = gid - m * 80;
  int type = c >> 4;
  int h = c & 15;
  const float* W; const float* bias; float extra = 0.f;
  switch (type) {
    case 0:  W = Wb;  bias = bb;  break;
    case 1:  W = Wfd; bias = bfd; extra = fdb[h]; break;
    case 2:  W = Wsd; bias = bsd; extra = sdb[h]; break;
    case 3:  W = Wfg; bias = bfg; break;
    default: W = Wsg; bias = bsg; break;
  }
  const float* hrow = hs + (size_t)m * 1024;
  float s = 0.f;
  for (int k2 = 0; k2 < 1024; ++k2)
    s = fmaf(hrow[k2], W[k2 * 16 + h], s);
  s += bias[h] + extra;
  float r = sigm_(s);
  int b = m >> 10, l = m & 1023;
  scl[((size_t)((b * 16 + h) * 1024 + l)) * 8 + type] = r;
}

// ---------------------------------------------------------------------------
// Pre-normalize q and k in place: x *= rsqrt(sum_64(x^2)+1e-6).
// One wave per 64-float row; q_ws and k_ws are contiguous (4M floats).
// ---------------------------------------------------------------------------
__global__ __launch_bounds__(256) void prenorm(float* __restrict__ p)
{
  int wid = blockIdx.x * 4 + (threadIdx.x >> 6);
  int lane = threadIdx.x & 63;
  size_t idx = (size_t)wid * 64 + lane;
  float x = p[idx];
  float ss = x * x;
#pragma unroll
  for (int d2 = 32; d2 >= 1; d2 >>= 1) ss += __shfl_xor(ss, d2, 64);
  p[idx] = x * rsqrtf(ss + 1e-6f);
}

// ---------------------------------------------------------------------------
// Sequential scan: ONE WAVE per (b,h). lane = output column. Rows of both
// states live in registers (Sf[64], Ss[64]). No barriers, no LDS. Decay and
// Frobenius cap are carried as scalars (af, as), refolded every 4 steps.
// k/q row values broadcast via v_readlane. Next step's k.S dot is fused
// into this step's update loop (ef1/es1), so each step is ONE register pass.
// ---------------------------------------------------------------------------
__global__ __launch_bounds__(64) void scan_kernel(
    const float* __restrict__ qg, const float* __restrict__ kg, const float* __restrict__ vg,
    const float* __restrict__ scl, const float* __restrict__ rfx, float* __restrict__ og)
{
  const int bh = blockIdx.x;   // 0..31
  const int lane = threadIdx.x;  // 0..63 : column index
  const float rf = rfx[0];

  float Sf[64], Ss[64];
#pragma unroll
  for (int j = 0; j < 64; ++j) { Sf[j] = 0.f; Ss[j] = 0.f; }

  const float* kb = kg + (size_t)bh * 65536;
  const float* qb = qg + (size_t)bh * 65536;
  const float* vb = vg + (size_t)bh * 65536;
  const float* sb = scl + (size_t)bh * 8192;
  const int b = bh >> 4, h = bh & 15;
  float* ob = og + (size_t)b * (1024 * 1024) + h * 64;  // + t*1024 + lane

  // pipeline registers: kcur=k_t, knxt=k_{t+1}, qcur=q_t, vv=v_t, sc=sc_t
  float kcur = kb[lane];
  float knxt = kb[64 + lane];
  float qcur = qb[lane];
  float vv   = vb[lane];
  float4 sc  = *(const float4*)&sb[0];
  float sg4  = sb[4];

  float af = 1.f, as = 1.f;   // carried scale: actual S = alpha * S'
  float ef = 0.f, es = 0.f;   // k_t . S' (computed in previous step's loop)

  for (int t = 0; t < 1024; ++t) {
    // ---- prefetch t+1 (q,v,sc) and t+2 (k) ----
    const int t1 = (t + 1) & 1023;
    const int t2 = (t + 2) & 1023;
    float knn = kb[t2 * 64 + lane];
    float qn  = qb[t1 * 64 + lane];
    float vn  = vb[t1 * 64 + lane];
    float4 scn = *(const float4*)&sb[(size_t)t1 * 8];
    float sgn = sb[(size_t)t1 * 8 + 4];

    const float bt = sc.x, fdt = sc.y, sdt = sc.z, fgt = sc.w, sgt = sg4;

    // ---- scalar head: decay into alpha, error, update coefficients ----
    af *= fdt; as *= sdt;
    const float raf = 1.f / af, ras = 1.f / as;
    const float errf = vv - af * ef;
    const float errs = vv - as * es;
    const float beff = bt * errf * raf;
    const float bess = bt * errs * ras;
    const float cfs = rf * as * raf;   // T'f = S'f + cfs*S's
    const float csf = rf * af * ras;   // T's = S's + csf*S'f

    // ---- one register pass over all 64 rows ----
    float nf = 0.f, ns = 0.f, of = 0.f, os = 0.f, ef1 = 0.f, es1 = 0.f;
#pragma unroll
    for (int r = 0; r < 64; ++r) {
      const float skb  = rdl_(kcur, r);
      const float skb1 = rdl_(knxt, r);
      const float sqb  = rdl_(qcur, r);
      const float sf = fmaf(skb, beff, Sf[r]);   // delta-rule update
      const float ssv = fmaf(skb, bess, Ss[r]);
      const float tf = fmaf(cfs, ssv, sf);       // resonance combine
      const float ts = fmaf(csf, sf, ssv);
      nf = fmaf(tf, tf, nf);                     // Frobenius partials
      ns = fmaf(ts, ts, ns);
      of = fmaf(sqb, tf, of);                    // q . T' (in-lane)
      os = fmaf(sqb, ts, os);
      ef1 = fmaf(skb1, tf, ef1);                 // fused next-step k . T'
      es1 = fmaf(skb1, ts, es1);
      Sf[r] = tf; Ss[r] = ts;
    }

    // ---- norm reduce (only cross-lane op per step) ----
#pragma unroll
    for (int d2 = 32; d2 >= 1; d2 >>= 1) {
      nf += __shfl_xor(nf, d2, 64);
      ns += __shfl_xor(ns, d2, 64);
    }
    const float nfr = af * sqrtf(nf);
    const float nsr = as * sqrtf(ns);
    const float scf = (nfr > 64.f) ? (64.f * raf * rsqrtf(nf)) * af : 1.f;
    const float scs = (nsr > 64.f) ? (64.f * ras * rsqrtf(ns)) * as : 1.f;
    // note: scf = 64/nfr computed via rsqrt; af*raf==1 kept for clarity
    af *= scf; as *= scs;

    // ---- output ----
    ob[(size_t)t * 1024 + lane] = fgt * af * of + sgt * as * os;

    // ---- periodic refold to keep alpha in fp32 range ----
    if ((t & 3) == 3) {
#pragma unroll
      for (int r = 0; r < 64; ++r) { Sf[r] *= af; Ss[r] *= as; }
      ef = af * ef1; es = as * es1;
      af = 1.f; as = 1.f;
    } else {
      ef = ef1; es = es1;
    }

    kcur = knxt; knxt = knn; qcur = qn; vv = vn; sc = scn; sg4 = sgn;
  }
}

// ---------------------------------------------------------------------------
// Gated RMSNorm: og = o * rsqrt(mean(o^2)+eps) * onorm_w * silu_g (g pre-silu'd)
// ---------------------------------------------------------------------------
__global__ __launch_bounds__(256) void rms_gate(
    const float* __restrict__ o, const float* __restrict__ gsil,
    const float* __restrict__ onw, float* __restrict__ og)
{
  int gi = blockIdx.x * 4 + (threadIdx.x >> 6);
  int lane = threadIdx.x & 63;
  size_t idx = (size_t)gi * 64 + lane;
  float x = o[idx];
  float ss = x * x;
#pragma unroll
  for (int d2 = 32; d2 >= 1; d2 >>= 1) ss += __shfl_xor(ss, d2, 64);
  float r = rsqrtf(ss * (1.f / 64.f) + 1e-5f);
  og[idx] = x * r * onw[lane] * gsil[idx];
}

// ---------------------------------------------------------------------------
// Host launcher
// ---------------------------------------------------------------------------
extern "C" void kernel_launch(void* const* d_in, const int* in_sizes, int n_in,
                              void* d_out, int out_size, void* d_ws, size_t ws_size,
                              hipStream_t stream)
{
  const float* hs  = (const float*)d_in[0];
  const float* Wq  = (const float*)d_in[1];
  const float* bq  = (const float*)d_in[2];
  const float* Wk  = (const float*)d_in[3];
  const float* bk  = (const float*)d_in[4];
  const float* Wv  = (const float*)d_in[5];
  const float* bv  = (const float*)d_in[6];
  const float* Wb  = (const float*)d_in[7];
  const float* bb  = (const float*)d_in[8];
  const float* Wfd = (const float*)d_in[9];
  const float* bfd = (const float*)d_in[10];
  const float* fdb = (const float*)d_in[11];
  const float* Wsd = (const float*)d_in[12];
  const float* bsd = (const float*)d_in[13];
  const float* sdb = (const float*)d_in[14];
  const float* Wfg = (const float*)d_in[15];
  const float* bfg = (const float*)d_in[16];
  const float* Wsg = (const float*)d_in[17];
  const float* bsg = (const float*)d_in[18];
  const float* Wg  = (const float*)d_in[19];
  const float* bg  = (const float*)d_in[20];
  const float* onw = (const float*)d_in[21];
  const float* Wo  = (const float*)d_in[22];
  const float* bo  = (const float*)d_in[23];
  const float* rfx = (const float*)d_in[24];

  float* ws = (float*)d_ws;
  const size_t TWO_M = (size_t)1 << 21;  // 2M floats = B*H*L*64
  float* q_ws  = ws;                     // q and k contiguous for prenorm
  float* k_ws  = ws + TWO_M;
  float* v_ws  = ws + 2 * TWO_M;
  float* g_ws  = ws + 3 * TWO_M;
  float* o_ws  = ws + 4 * TWO_M;
  float* scl_ws = ws + 5 * TWO_M;        // 32*1024*8 floats packed scalars
  float* og_ws = q_ws;  // reuse q buffer (scan has consumed it)

  // 1) big projections: q,k,v (silu + scatter), g (silu, linear)
  GemmBatch gb1;
  gb1.s[0].W = Wq; gb1.s[0].bias = bq; gb1.s[0].out = q_ws; gb1.s[0].mode = 2;
  gb1.s[1].W = Wk; gb1.s[1].bias = bk; gb1.s[1].out = k_ws; gb1.s[1].mode = 2;
  gb1.s[2].W = Wv; gb1.s[2].bias = bv; gb1.s[2].out = v_ws; gb1.s[2].mode = 2;
  gb1.s[3].W = Wg; gb1.s[3].bias = bg; gb1.s[3].out = g_ws; gb1.s[3].mode = 1;
  gemm_act<<<dim3(32, 16, 4), 256, 0, stream>>>(hs, gb1, 2048, 1024, 1024);

  // 2) per-head scalar projections (packed)
  scalar_proj<<<640, 256, 0, stream>>>(hs, Wb, bb, Wfd, bfd, fdb, Wsd, bsd, sdb,
                                       Wfg, bfg, Wsg, bsg, scl_ws);

  // 3) pre-normalize q,k (contiguous 4M floats = 65536 rows of 64)
  prenorm<<<16384, 256, 0, stream>>>(q_ws);

  // 4) sequential dual-state delta-rule scan (1 wave per (b,h))
  scan_kernel<<<32, 64, 0, stream>>>(q_ws, k_ws, v_ws, scl_ws, rfx, o_ws);

  // 5) gated RMSNorm
  rms_gate<<<8192, 256, 0, stream>>>(o_ws, g_ws, onw, og_ws);

  // 6) output projection -> d_out
  GemmBatch gb2;
  gb2.s[0].W = Wo; gb2.s[0].bias = bo; gb2.s[0].out = (float*)d_out; gb2.s[0].mode = 0;
  gb2.s[1] = gb2.s[0]; gb2.s[2] = gb2.s[0]; gb2.s[3] = gb2.s[0];
  gemm_act<<<dim3(32, 16, 1), 256, 0, stream>>>(og_ws, gb2, 2048, 1024, 1024);
}

// Round 4
// 2060.902 us; speedup vs baseline: 1.6212x; 1.6212x over previous
//
#include <hip/hip_runtime.h>

// ---------------------------------------------------------------------------
// Problem constants: B=2, L=1024, D=1024, H=16, DK=DV=64
// ---------------------------------------------------------------------------

#define TILE_M 64
#define TILE_N 64
#define TILE_K 16

struct GemmSlot { const float* W; const float* bias; float* out; int mode; };
struct GemmBatch { GemmSlot s[4]; };

__device__ __forceinline__ float silu_(float x) {
  return x / (1.f + __expf(-x));
}
__device__ __forceinline__ float sigm_(float x) {
  return 1.f / (1.f + __expf(-x));
}
__device__ __forceinline__ float rdl_(float v, int l) {
  return __int_as_float(__builtin_amdgcn_readlane(__float_as_int(v), l));
}

// ---------------------------------------------------------------------------
// Generic fp32 GEMM: C = act(A[M,K] @ W[K,N] + bias), act/store per mode.
// mode 0: raw, linear store; mode 1: silu, linear; mode 2: silu, scatter BHLd
// ---------------------------------------------------------------------------
__global__ __launch_bounds__(256) void gemm_act(
    const float* __restrict__ A, GemmBatch gb, int M, int N, int K)
{
  const GemmSlot sl = gb.s[blockIdx.z];
  const float* __restrict__ W = sl.W;

  __shared__ float As[TILE_K][TILE_M + 4];
  __shared__ float Ws[TILE_K][TILE_N];

  const int tid = threadIdx.x;
  const int bm = blockIdx.x * TILE_M;
  const int bn = blockIdx.y * TILE_N;
  const int tm = (tid >> 4) << 2;
  const int tn = (tid & 15) << 2;
  const int la_r = tid >> 2;
  const int la_c = (tid & 3) << 2;
  const int lw_r = tid >> 4;
  const int lw_c = (tid & 15) << 2;

  float acc[4][4] = {{0.f,0.f,0.f,0.f},{0.f,0.f,0.f,0.f},
                     {0.f,0.f,0.f,0.f},{0.f,0.f,0.f,0.f}};

  for (int kb = 0; kb < K; kb += TILE_K) {
    float4 av = *(const float4*)&A[(size_t)(bm + la_r) * K + kb + la_c];
    float4 wv = *(const float4*)&W[(size_t)(kb + lw_r) * N + bn + lw_c];
    __syncthreads();
    As[la_c + 0][la_r] = av.x;
    As[la_c + 1][la_r] = av.y;
    As[la_c + 2][la_r] = av.z;
    As[la_c + 3][la_r] = av.w;
    *(float4*)&Ws[lw_r][lw_c] = wv;
    __syncthreads();
#pragma unroll
    for (int kk = 0; kk < TILE_K; ++kk) {
      float4 a = *(const float4*)&As[kk][tm];
      float4 b = *(const float4*)&Ws[kk][tn];
      acc[0][0] = fmaf(a.x, b.x, acc[0][0]);
      acc[0][1] = fmaf(a.x, b.y, acc[0][1]);
      acc[0][2] = fmaf(a.x, b.z, acc[0][2]);
      acc[0][3] = fmaf(a.x, b.w, acc[0][3]);
      acc[1][0] = fmaf(a.y, b.x, acc[1][0]);
      acc[1][1] = fmaf(a.y, b.y, acc[1][1]);
      acc[1][2] = fmaf(a.y, b.z, acc[1][2]);
      acc[1][3] = fmaf(a.y, b.w, acc[1][3]);
      acc[2][0] = fmaf(a.z, b.x, acc[2][0]);
      acc[2][1] = fmaf(a.z, b.y, acc[2][1]);
      acc[2][2] = fmaf(a.z, b.z, acc[2][2]);
      acc[2][3] = fmaf(a.z, b.w, acc[2][3]);
      acc[3][0] = fmaf(a.w, b.x, acc[3][0]);
      acc[3][1] = fmaf(a.w, b.y, acc[3][1]);
      acc[3][2] = fmaf(a.w, b.z, acc[3][2]);
      acc[3][3] = fmaf(a.w, b.w, acc[3][3]);
    }
  }

  const float* bias = sl.bias;
  float* out = sl.out;
  const int mode = sl.mode;
#pragma unroll
  for (int i = 0; i < 4; ++i) {
#pragma unroll
    for (int j = 0; j < 4; ++j) {
      int m = bm + tm + i, n = bn + tn + j;
      float c = acc[i][j] + bias[n];
      if (mode >= 1) c = silu_(c);
      if (mode == 2) {
        int h = n >> 6, d = n & 63;
        int b = m >> 10, l = m & 1023;
        out[(((size_t)(b * 16 + h)) * 1024 + l) * 64 + d] = c;
      } else {
        out[(size_t)m * N + n] = c;
      }
    }
  }
}

// ---------------------------------------------------------------------------
// Scalar projections, packed: scl[bh][t][8], slot 0=beta,1=fd,2=sd,3=fg,4=sg
// ---------------------------------------------------------------------------
__global__ __launch_bounds__(256) void scalar_proj(
    const float* __restrict__ hs,
    const float* __restrict__ Wb,  const float* __restrict__ bb,
    const float* __restrict__ Wfd, const float* __restrict__ bfd, const float* __restrict__ fdb,
    const float* __restrict__ Wsd, const float* __restrict__ bsd, const float* __restrict__ sdb,
    const float* __restrict__ Wfg, const float* __restrict__ bfg,
    const float* __restrict__ Wsg, const float* __restrict__ bsg,
    float* __restrict__ scl)
{
  int gid = blockIdx.x * 256 + threadIdx.x;  // < 2048*80
  int m = gid / 80;
  int c = gid - m * 80;
  int type = c >> 4;
  int h = c & 15;
  const float* W; const float* bias; float extra = 0.f;
  switch (type) {
    case 0:  W = Wb;  bias = bb;  break;
    case 1:  W = Wfd; bias = bfd; extra = fdb[h]; break;
    case 2:  W = Wsd; bias = bsd; extra = sdb[h]; break;
    case 3:  W = Wfg; bias = bfg; break;
    default: W = Wsg; bias = bsg; break;
  }
  const float* hrow = hs + (size_t)m * 1024;
  float s = 0.f;
  for (int k2 = 0; k2 < 1024; ++k2)
    s = fmaf(hrow[k2], W[k2 * 16 + h], s);
  s += bias[h] + extra;
  float r = sigm_(s);
  int b = m >> 10, l = m & 1023;
  scl[((size_t)((b * 16 + h) * 1024 + l)) * 8 + type] = r;
}

// ---------------------------------------------------------------------------
// Pre-normalize q and k in place: x *= rsqrt(sum_64(x^2)+1e-6).
// ---------------------------------------------------------------------------
__global__ __launch_bounds__(256) void prenorm(float* __restrict__ p)
{
  int wid = blockIdx.x * 4 + (threadIdx.x >> 6);
  int lane = threadIdx.x & 63;
  size_t idx = (size_t)wid * 64 + lane;
  float x = p[idx];
  float ss = x * x;
#pragma unroll
  for (int d2 = 32; d2 >= 1; d2 >>= 1) ss += __shfl_xor(ss, d2, 64);
  p[idx] = x * rsqrtf(ss + 1e-6f);
}

// ---------------------------------------------------------------------------
// Sequential scan: ONE WAVE per (b,h), __launch_bounds__(64,1) so the full
// 512-VGPR budget is available (Sf[64]+Ss[64] = 128 VGPRs must NOT spill).
// lane = output column; state rows in registers; k/q broadcast via readlane.
// Frobenius norms and the cross inner product <Sf,Ss> are tracked
// ANALYTICALLY as scalars (Nf, Ns, C) via closed-form recurrences, so the
// 64-row register pass has no norm accumulation and the only cross-lane
// reduce (6 values) is OFF the row-pass critical path.
// ---------------------------------------------------------------------------
__global__ __launch_bounds__(64, 1) void scan_kernel(
    const float* __restrict__ qg, const float* __restrict__ kg, const float* __restrict__ vg,
    const float* __restrict__ scl, const float* __restrict__ rfx, float* __restrict__ og)
{
  const int bh = blockIdx.x;     // 0..31
  const int lane = threadIdx.x;  // 0..63 : column index
  const float rf = rfx[0];
  const float rf2 = rf * rf;

  float Sf[64], Ss[64];
#pragma unroll
  for (int j = 0; j < 64; ++j) { Sf[j] = 0.f; Ss[j] = 0.f; }

  const float* kb = kg + (size_t)bh * 65536;
  const float* qb = qg + (size_t)bh * 65536;
  const float* vb = vg + (size_t)bh * 65536;
  const float* sb = scl + (size_t)bh * 8192;
  const int b = bh >> 4, h = bh & 15;
  float* ob = og + (size_t)b * (1024 * 1024) + h * 64;  // + t*1024 + lane

  // pipeline registers
  float kcur = kb[lane];
  float knxt = kb[64 + lane];
  float qcur = qb[lane];
  float vv   = vb[lane];
  float4 sc  = *(const float4*)&sb[0];
  float sg4  = sb[4];

  float af = 1.f, as = 1.f;    // lazy scale: actual S = alpha * S'
  float ef = 0.f, es = 0.f;    // per-lane k_t . S' (from prev row pass)
  float Nf = 0.f, Ns = 0.f, Cc = 0.f;  // analytic ||Sf||^2, ||Ss||^2, <Sf,Ss>

  for (int t = 0; t < 1024; ++t) {
    // ---- prefetch t+1 (q,v,sc) and t+2 (k) ----
    const int t1 = (t + 1) & 1023;
    const int t2 = (t + 2) & 1023;
    float knn = kb[t2 * 64 + lane];
    float qn  = qb[t1 * 64 + lane];
    float vn  = vb[t1 * 64 + lane];
    float4 scn = *(const float4*)&sb[(size_t)t1 * 8];
    float sgn = sb[(size_t)t1 * 8 + 4];

    const float bt = sc.x, fdt = sc.y, sdt = sc.z, fgt = sc.w, sgt = sg4;

    // ---- scalar head: decay, per-lane error, update coefficients ----
    af *= fdt; as *= sdt;
    const float raf = 1.f / af, ras = 1.f / as;
    const float EF = af * ef, ES = as * es;     // actual-scale dots
    const float errf = vv - EF;
    const float errs = vv - ES;
    const float beff = bt * errf * raf;         // per-lane VGPR coeff
    const float bess = bt * errs * ras;
    const float cfs = rf * as * raf;            // uniform combine coeffs
    const float csf = rf * af * ras;

    // ---- analytic norm ingredients (per-lane, reduce overlaps row pass) ----
    float A1 = EF * errf;                // -> sum_c EF.errf
    float A2 = ES * errs;
    float A3 = errf * errf;
    float A4 = errs * errs;
    float A5 = errf * errs;
    float A67 = errs * EF + errf * ES;   // combined cross term

    // ---- one register pass over all 64 rows ----
    float of = 0.f, os = 0.f, ef1 = 0.f, es1 = 0.f;
#pragma unroll
    for (int r = 0; r < 64; ++r) {
      const float skb  = rdl_(kcur, r);
      const float skb1 = rdl_(knxt, r);
      const float sqb  = rdl_(qcur, r);
      const float sf = fmaf(skb, beff, Sf[r]);   // delta-rule update
      const float sv = fmaf(skb, bess, Ss[r]);
      const float tf = fmaf(cfs, sv, sf);        // resonance combine
      const float ts = fmaf(csf, sf, sv);
      of  = fmaf(sqb, tf, of);                   // q . T'
      os  = fmaf(sqb, ts, os);
      ef1 = fmaf(skb1, tf, ef1);                 // fused next-step k . T'
      es1 = fmaf(skb1, ts, es1);
      Sf[r] = tf; Ss[r] = ts;
    }

    // ---- reduce the 6 norm ingredients across lanes ----
#pragma unroll
    for (int d2 = 32; d2 >= 1; d2 >>= 1) {
      A1 += __shfl_xor(A1, d2, 64);
      A2 += __shfl_xor(A2, d2, 64);
      A3 += __shfl_xor(A3, d2, 64);
      A4 += __shfl_xor(A4, d2, 64);
      A5 += __shfl_xor(A5, d2, 64);
      A67 += __shfl_xor(A67, d2, 64);
    }

    // ---- closed-form norm recurrences ----
    const float b2 = bt * bt;
    const float Nfd = fmaf(fdt * fdt, Nf, fmaf(2.f * bt, A1, b2 * A3));
    const float Nsd = fmaf(sdt * sdt, Ns, fmaf(2.f * bt, A2, b2 * A4));
    const float Cd  = fmaf(fdt * sdt, Cc, fmaf(bt, A67, b2 * A5));
    const float NTf = Nfd + 2.f * rf * Cd + rf2 * Nsd;
    const float NTs = Nsd + 2.f * rf * Cd + rf2 * Nfd;
    const float CT  = (1.f + rf2) * Cd + rf * (Nfd + Nsd);
    const bool capf = NTf > 4096.f;
    const bool caps = NTs > 4096.f;
    const float scf = capf ? 64.f * rsqrtf(NTf) : 1.f;
    const float scs = caps ? 64.f * rsqrtf(NTs) : 1.f;
    af *= scf; as *= scs;
    Nf = capf ? 4096.f : NTf;
    Ns = caps ? 4096.f : NTs;
    Cc = scf * scs * CT;

    // ---- output ----
    ob[(size_t)t * 1024 + lane] = fgt * af * of + sgt * as * os;

    // ---- periodic refold to keep alpha in fp32 range ----
    if ((t & 3) == 3) {
#pragma unroll
      for (int r = 0; r < 64; ++r) { Sf[r] *= af; Ss[r] *= as; }
      ef = af * ef1; es = as * es1;
      af = 1.f; as = 1.f;
    } else {
      ef = ef1; es = es1;
    }

    kcur = knxt; knxt = knn; qcur = qn; vv = vn; sc = scn; sg4 = sgn;
  }
}

// ---------------------------------------------------------------------------
// Gated RMSNorm: og = o * rsqrt(mean(o^2)+eps) * onorm_w * silu_g (g pre-silu'd)
// ---------------------------------------------------------------------------
__global__ __launch_bounds__(256) void rms_gate(
    const float* __restrict__ o, const float* __restrict__ gsil,
    const float* __restrict__ onw, float* __restrict__ og)
{
  int gi = blockIdx.x * 4 + (threadIdx.x >> 6);
  int lane = threadIdx.x & 63;
  size_t idx = (size_t)gi * 64 + lane;
  float x = o[idx];
  float ss = x * x;
#pragma unroll
  for (int d2 = 32; d2 >= 1; d2 >>= 1) ss += __shfl_xor(ss, d2, 64);
  float r = rsqrtf(ss * (1.f / 64.f) + 1e-5f);
  og[idx] = x * r * onw[lane] * gsil[idx];
}

// ---------------------------------------------------------------------------
// Host launcher
// ---------------------------------------------------------------------------
extern "C" void kernel_launch(void* const* d_in, const int* in_sizes, int n_in,
                              void* d_out, int out_size, void* d_ws, size_t ws_size,
                              hipStream_t stream)
{
  const float* hs  = (const float*)d_in[0];
  const float* Wq  = (const float*)d_in[1];
  const float* bq  = (const float*)d_in[2];
  const float* Wk  = (const float*)d_in[3];
  const float* bk  = (const float*)d_in[4];
  const float* Wv  = (const float*)d_in[5];
  const float* bv  = (const float*)d_in[6];
  const float* Wb  = (const float*)d_in[7];
  const float* bb  = (const float*)d_in[8];
  const float* Wfd = (const float*)d_in[9];
  const float* bfd = (const float*)d_in[10];
  const float* fdb = (const float*)d_in[11];
  const float* Wsd = (const float*)d_in[12];
  const float* bsd = (const float*)d_in[13];
  const float* sdb = (const float*)d_in[14];
  const float* Wfg = (const float*)d_in[15];
  const float* bfg = (const float*)d_in[16];
  const float* Wsg = (const float*)d_in[17];
  const float* bsg = (const float*)d_in[18];
  const float* Wg  = (const float*)d_in[19];
  const float* bg  = (const float*)d_in[20];
  const float* onw = (const float*)d_in[21];
  const float* Wo  = (const float*)d_in[22];
  const float* bo  = (const float*)d_in[23];
  const float* rfx = (const float*)d_in[24];

  float* ws = (float*)d_ws;
  const size_t TWO_M = (size_t)1 << 21;  // 2M floats = B*H*L*64
  float* q_ws  = ws;                     // q and k contiguous for prenorm
  float* k_ws  = ws + TWO_M;
  float* v_ws  = ws + 2 * TWO_M;
  float* g_ws  = ws + 3 * TWO_M;
  float* o_ws  = ws + 4 * TWO_M;
  float* scl_ws = ws + 5 * TWO_M;        // 32*1024*8 floats packed scalars
  float* og_ws = q_ws;  // reuse q buffer (scan has consumed it)

  // 1) big projections: q,k,v (silu + scatter), g (silu, linear)
  GemmBatch gb1;
  gb1.s[0].W = Wq; gb1.s[0].bias = bq; gb1.s[0].out = q_ws; gb1.s[0].mode = 2;
  gb1.s[1].W = Wk; gb1.s[1].bias = bk; gb1.s[1].out = k_ws; gb1.s[1].mode = 2;
  gb1.s[2].W = Wv; gb1.s[2].bias = bv; gb1.s[2].out = v_ws; gb1.s[2].mode = 2;
  gb1.s[3].W = Wg; gb1.s[3].bias = bg; gb1.s[3].out = g_ws; gb1.s[3].mode = 1;
  gemm_act<<<dim3(32, 16, 4), 256, 0, stream>>>(hs, gb1, 2048, 1024, 1024);

  // 2) per-head scalar projections (packed)
  scalar_proj<<<640, 256, 0, stream>>>(hs, Wb, bb, Wfd, bfd, fdb, Wsd, bsd, sdb,
                                       Wfg, bfg, Wsg, bsg, scl_ws);

  // 3) pre-normalize q,k (contiguous 4M floats = 65536 rows of 64)
  prenorm<<<16384, 256, 0, stream>>>(q_ws);

  // 4) sequential dual-state delta-rule scan (1 wave per (b,h))
  scan_kernel<<<32, 64, 0, stream>>>(q_ws, k_ws, v_ws, scl_ws, rfx, o_ws);

  // 5) gated RMSNorm
  rms_gate<<<8192, 256, 0, stream>>>(o_ws, g_ws, onw, og_ws);

  // 6) output projection -> d_out
  GemmBatch gb2;
  gb2.s[0].W = Wo; gb2.s[0].bias = bo; gb2.s[0].out = (float*)d_out; gb2.s[0].mode = 0;
  gb2.s[1] = gb2.s[0]; gb2.s[2] = gb2.s[0]; gb2.s[3] = gb2.s[0];
  gemm_act<<<dim3(32, 16, 1), 256, 0, stream>>>(og_ws, gb2, 2048, 1024, 1024);
}